// Round 1
// baseline (331.099 us; speedup 1.0000x reference)
//
#include <hip/hip_runtime.h>
#include <hip/hip_fp16.h>
#include <math.h>

constexpr int D = 128;

struct __align__(16) H8 { __half2 h[4]; };

typedef _Float16     half8   __attribute__((ext_vector_type(8)));
typedef float        floatx4 __attribute__((ext_vector_type(4)));
typedef unsigned int uint4v  __attribute__((ext_vector_type(4)));
typedef unsigned int uint2v  __attribute__((ext_vector_type(2)));

// ---------------- preprocessing ----------------

__device__ __forceinline__ int detect64(const int* __restrict__ ei) {
  int z = 0;
#pragma unroll
  for (int i = 0; i < 8; ++i) z |= ei[2 * i + 1];
  return (z == 0) ? 1 : 0;
}

__device__ __forceinline__ void load_edge(const int* __restrict__ ei, int e, int nE,
                                          int m64, int n, int& r, int& c) {
  if (m64) { r = ei[2 * (size_t)e]; c = ei[2 * ((size_t)nE + e)]; }
  else     { r = ei[(size_t)e];     c = ei[(size_t)nE + e]; }
  r = min(max(r, 0), n - 1);
  c = min(max(c, 0), n - 1);
}

// blocks 0..23: transpose W1/W2/W3 (fp32 [k][n]) -> Wt fp16 [n][k], 8 blocks per matrix.
// blocks 24.. : zero cnt (int) and deg (float).
__global__ void k_setup(const float* __restrict__ W1, const float* __restrict__ W2,
                        const float* __restrict__ W3, __half* __restrict__ Wt,
                        int* __restrict__ cnt, float* __restrict__ deg, int n) {
  int b = blockIdx.x;
  if (b < 24) {
    int m = b >> 3, s = b & 7;
    const float* W = m == 0 ? W1 : (m == 1 ? W2 : W3);
    __half* o = Wt + (size_t)m * D * D;
    int t = threadIdx.x;
    int nn = t & 127;          // output row (input col)
    int kh = t >> 7;           // 0/1: which 8-wide k group
    int k0 = s * 16 + kh * 8;
    H8 hv;
#pragma unroll
    for (int jj = 0; jj < 4; ++jj) {
      float f0 = W[(size_t)(k0 + 2 * jj)     * D + nn];
      float f1 = W[(size_t)(k0 + 2 * jj + 1) * D + nn];
      hv.h[jj] = __floats2half2_rn(f0, f1);
    }
    *(H8*)(o + (size_t)nn * D + k0) = hv;
  } else {
    int i = (b - 24) * 256 + threadIdx.x;
    if (i < n) { cnt[i] = 0; deg[i] = 0.f; }
  }
}

// counts + weighted in-degree (float atomics) + cache decoded edges
__global__ void k_pos(const int* __restrict__ ei, const float* __restrict__ w,
                      int* __restrict__ cnt, float* __restrict__ deg,
                      int2* __restrict__ rc, int* __restrict__ pos, int nE, int n) {
  int e = blockIdx.x * blockDim.x + threadIdx.x;
  if (e >= nE) return;
  int m64 = detect64(ei);
  int r, c;
  load_edge(ei, e, nE, m64, n, r, c);
  rc[e] = make_int2(r, c);
  pos[e] = atomicAdd(&cnt[c], 1);
  atomicAdd(&deg[c], w[e]);
}

// exclusive scan of PADDED counts (each node's slot count rounded up to x4
// so every per-node edge range is 16B-aligned for uint4 coef loads)
__global__ void k_scan1(const int* __restrict__ cnt, int* __restrict__ offs,
                        int* __restrict__ bsum, int n) {
  __shared__ int s[256];
  int t = threadIdx.x;
  int i = blockIdx.x * 256 + t;
  int v = (i < n) ? ((cnt[i] + 3) & ~3) : 0;
  s[t] = v;
  __syncthreads();
  for (int off = 1; off < 256; off <<= 1) {
    int x = 0;
    if (t >= off) x = s[t - off];
    __syncthreads();
    if (t >= off) s[t] += x;
    __syncthreads();
  }
  if (i < n) offs[i] = s[t] - v;
  if (t == 255) bsum[blockIdx.x] = s[255];
}

__global__ void k_scan2(const int* __restrict__ bsum, int* __restrict__ boff, int nb) {
  __shared__ int s[256];
  int t = threadIdx.x;
  int v = (t < nb) ? bsum[t] : 0;
  s[t] = v;
  __syncthreads();
  for (int off = 1; off < 256; off <<= 1) {
    int x = 0;
    if (t >= off) x = s[t - off];
    __syncthreads();
    if (t >= off) s[t] += x;
    __syncthreads();
  }
  if (t < nb) boff[t] = s[t] - v;
}

// finish scan + elementwise dinv = rsqrt(1 + weighted_deg)
__global__ void k_scan3(int* __restrict__ offs, const int* __restrict__ boff,
                        const int* __restrict__ bsum, const float* __restrict__ deg,
                        float* __restrict__ dinv, int n, int nb) {
  int i = blockIdx.x * 256 + threadIdx.x;
  if (i < n) {
    offs[i] += boff[blockIdx.x];
    dinv[i] = rsqrtf(1.0f + deg[i]);
  }
  if (i == 0) offs[n] = boff[nb - 1] + bsum[nb - 1];
}

// scatter packed edges (src<<16 | fp16(dinv[src]*w)) into padded CSR;
// node-parallel part zeroes the pad slots (coef 0 -> no-op in agg).
__global__ void k_fill(const int2* __restrict__ rc, const int* __restrict__ pos,
                       const float* __restrict__ w, const int* __restrict__ offs,
                       const int* __restrict__ cnt, const float* __restrict__ dinv,
                       unsigned int* __restrict__ ecf2, int nE, int n) {
  int e = blockIdx.x * blockDim.x + threadIdx.x;
  if (e < nE) {
    int2 p = rc[e];
    int idx = offs[p.y] + pos[e];
    float cf = dinv[p.x] * w[e];
    ecf2[idx] = ((unsigned int)p.x << 16) |
                (unsigned int)__half_as_ushort(__float2half_rn(cf));
  }
  if (e < n) {
    int q0 = offs[e] + cnt[e], q1 = offs[e + 1];
    for (int q = q0; q < q1; ++q) ecf2[q] = 0;
  }
}

// ---------------- MFMA GEMM: Y(chunk layout) = half( act(A) @ W ) ----------------
template <int ACT>
__device__ __forceinline__ float act_f(float x) {
  if (ACT == 1) return x > 0.f ? x : expm1f(x);
  if (ACT == 2) return 0.5f * x * (1.0f + erff(x * 0.70710678118654752440f));
  return x;
}

template <int ACT, typename AT>
__global__ __launch_bounds__(256) void k_gemm(const AT* __restrict__ A,
                                              const __half* __restrict__ Wt,
                                              __half* __restrict__ Y, int n) {
  const int wave = threadIdx.x >> 6;
  const int lane = threadIdx.x & 63;
  const int np = lane & 15;
  const int quad = lane >> 4;
  const int node = blockIdx.x * 64 + wave * 16 + np;
  const int nc = min(node, n - 1);

  // B-operand frags: b[s] = act(A[node][s*32 + quad*8 .. +7]) as fp16
  half8 b[4];
#pragma unroll
  for (int s = 0; s < 4; ++s) {
    if constexpr (sizeof(AT) == 4) {
      const float* ap = (const float*)A + (size_t)nc * D + s * 32 + quad * 8;
      floatx4 v0 = __builtin_nontemporal_load((const floatx4*)ap);
      floatx4 v1 = __builtin_nontemporal_load((const floatx4*)(ap + 4));
#pragma unroll
      for (int t = 0; t < 4; ++t) {
        b[s][t]     = (_Float16)act_f<ACT>(v0[t]);
        b[s][t + 4] = (_Float16)act_f<ACT>(v1[t]);
      }
    } else {
      // chunk layout: chunk s, node nc, halves quad*8..+7
      half8 raw = __builtin_nontemporal_load(
          (const half8*)((const __half*)A + ((size_t)s * n + nc) * 32 + quad * 8));
#pragma unroll
      for (int t = 0; t < 8; ++t)
        b[s][t] = (_Float16)act_f<ACT>((float)raw[t]);
    }
  }

  floatx4 acc[8];
#pragma unroll
  for (int mt = 0; mt < 8; ++mt) acc[mt] = (floatx4){0.f, 0.f, 0.f, 0.f};

#pragma unroll
  for (int mt = 0; mt < 8; ++mt) {
#pragma unroll
    for (int s = 0; s < 4; ++s) {
      half8 a = *(const half8*)(Wt + (size_t)(mt * 16 + np) * D + s * 32 + quad * 8);
      acc[mt] = __builtin_amdgcn_mfma_f32_16x16x32_f16(a, b[s], acc[mt], 0, 0, 0);
    }
  }

  if (node < n) {
#pragma unroll
    for (int mt = 0; mt < 8; ++mt) {
      __half2 ha = __floats2half2_rn(acc[mt][0], acc[mt][1]);
      __half2 hb = __floats2half2_rn(acc[mt][2], acc[mt][3]);
      uint2v pv;
      pv[0] = *(unsigned int*)&ha;
      pv[1] = *(unsigned int*)&hb;
      int f0 = mt * 16 + quad * 4;
      __builtin_nontemporal_store(
          pv, (uint2v*)(Y + ((size_t)(f0 >> 5) * n + node) * 32 + (f0 & 31)));
    }
  }
}

// -------- aggregation (chunked): per chunk c, OUT[:,c*32..] = dc*(sum coef*Yc[r] + dc*Yc[node]) + b
// node-group = 8 lanes: 2 edge-subs x 4 j-lanes (16B each) => one 64B line per edge gather.
// chunk = blockIdx & 3 -> round-robin block->XCD pins one chunk class per XCD
// (per-XCD gather working set = N*64B = 3.2MB < 4MB L2; ecf2/output streamed non-temporal
//  so they don't evict the gather set).
__device__ __forceinline__ void fmacc8(float* acc, float c, const H8& y) {
  const _Float16* hp = (const _Float16*)&y;
#pragma unroll
  for (int i = 0; i < 8; ++i) acc[i] = fmaf(c, (float)hp[i], acc[i]);  // v_fma_mix_f32
}

__device__ __forceinline__ float cdecode(unsigned int u) {
  return __half2float(__ushort_as_half((unsigned short)(u & 0xffffu)));
}

template <int PRELU, typename OutT>
__global__ __launch_bounds__(256) void k_agg(const __half* __restrict__ Y,
                                             const int* __restrict__ offs,
                                             const unsigned int* __restrict__ ecf2,
                                             const float* __restrict__ dinv,
                                             const float* __restrict__ bias,
                                             const float* __restrict__ pw,
                                             OutT* __restrict__ OUT, int n) {
  const int chunk = blockIdx.x & 3;
  const int t = threadIdx.x;
  const int node = (blockIdx.x >> 2) * 32 + (t >> 3);
  const int sub = (t >> 2) & 1;   // edge half-range
  const int j = t & 3;            // 16B piece of the 64B chunk row
  if (node >= n) return;
  const __half* Yc = Y + (size_t)chunk * n * 32;
  float dc = dinv[node];
  float acc[8] = {0.f, 0.f, 0.f, 0.f, 0.f, 0.f, 0.f, 0.f};
  if (sub == 0) {
    H8 ys = *(const H8*)(Yc + (size_t)node * 32 + j * 8);
    fmacc8(acc, dc, ys);
  }
  int lo = offs[node], hi = offs[node + 1];       // padded to x4, 16B aligned
  int nb4 = (hi - lo) >> 2;
  int em = lo + (((nb4 + 1) >> 1) << 2);          // sub0: [lo,em)  sub1: [em,hi)
  int b0 = sub ? em : lo;
  int b1 = sub ? hi : em;
  for (int b = b0; b < b1; b += 4) {
    uint4v u = __builtin_nontemporal_load((const uint4v*)(ecf2 + b));
    H8 y0 = *(const H8*)(Yc + (size_t)(u[0] >> 16) * 32 + j * 8);
    H8 y1 = *(const H8*)(Yc + (size_t)(u[1] >> 16) * 32 + j * 8);
    H8 y2 = *(const H8*)(Yc + (size_t)(u[2] >> 16) * 32 + j * 8);
    H8 y3 = *(const H8*)(Yc + (size_t)(u[3] >> 16) * 32 + j * 8);
    fmacc8(acc, cdecode(u[0]), y0);
    fmacc8(acc, cdecode(u[1]), y1);
    fmacc8(acc, cdecode(u[2]), y2);
    fmacc8(acc, cdecode(u[3]), y3);
  }
  // combine the two subs (lanes differ in bit 2): each lane keeps its own 4
  // features and receives the partner's contribution for those 4 only.
  floatx4 b4 = *(const floatx4*)(bias + chunk * 32 + j * 8 + sub * 4);
  float o[4];
#pragma unroll
  for (int i = 0; i < 4; ++i) {
    float mine  = sub ? acc[4 + i] : acc[i];
    float other = sub ? acc[i]     : acc[4 + i];
    float recv = __shfl_xor(other, 4, 64);
    o[i] = dc * (mine + recv) + b4[i];
  }
  if (PRELU) {
    float wv = *pw;
#pragma unroll
    for (int i = 0; i < 4; ++i) o[i] = o[i] >= 0.f ? o[i] : wv * o[i];
  }
  if constexpr (sizeof(OutT) == 4) {
    floatx4 ov = {o[0], o[1], o[2], o[3]};
    __builtin_nontemporal_store(
        ov, (floatx4*)((float*)OUT + (size_t)node * D + chunk * 32 + j * 8 + sub * 4));
  } else {
    __half2 ha = __floats2half2_rn(o[0], o[1]);
    __half2 hb = __floats2half2_rn(o[2], o[3]);
    uint2v pv;
    pv[0] = *(unsigned int*)&ha;
    pv[1] = *(unsigned int*)&hb;
    __builtin_nontemporal_store(
        pv, (uint2v*)((__half*)OUT + ((size_t)chunk * n + node) * 32 + j * 8 + sub * 4));
  }
}

// ---------------- launch ----------------
extern "C" void kernel_launch(void* const* d_in, const int* in_sizes, int n_in,
                              void* d_out, int out_size, void* d_ws, size_t ws_size,
                              hipStream_t stream) {
  const float* x  = (const float*)d_in[0];
  const int*   ei = (const int*)d_in[1];
  const float* w  = (const float*)d_in[2];
  const float* W1 = (const float*)d_in[3];
  const float* b1 = (const float*)d_in[4];
  const float* W2 = (const float*)d_in[5];
  const float* b2 = (const float*)d_in[6];
  const float* W3 = (const float*)d_in[7];
  const float* b3 = (const float*)d_in[8];
  const float* pw = (const float*)d_in[9];
  const int N = in_sizes[0] / D;
  const int E = in_sizes[2];
  float* out = (float*)d_out;

  char* wsb = (char*)d_ws;
  size_t off = 0;
  auto alloc = [&](size_t bytes) {
    void* p = wsb + off;
    off = (off + bytes + 255) & ~(size_t)255;
    return p;
  };
  float*        dinv = (float*)alloc((size_t)N * 4);
  float*        deg  = (float*)alloc((size_t)N * 4);
  int*          cnt  = (int*)alloc((size_t)N * 4);
  int*          offs = (int*)alloc((size_t)(N + 1) * 4);
  int*          bsum = (int*)alloc(256 * 4);
  int*          boff = (int*)alloc(256 * 4);
  unsigned int* ecf2 = (unsigned int*)alloc(((size_t)E + 3 * (size_t)N + 64) * 4);
  __half*       Wt   = (__half*)alloc((size_t)3 * D * D * 2);
  __half*       Y    = (__half*)alloc((size_t)N * D * 2);
  __half*       h    = (__half*)alloc((size_t)N * D * 2);
  // transient buffers aliased into Y (dead before first GEMM writes Y): 12B/edge < N*D*2
  int2*         rc   = (int2*)Y;
  int*          pos  = (int*)((char*)Y + (size_t)E * 8);

  const int nbN = (N + 255) / 256;
  const int eb  = (E + 255) / 256;
  const int fb  = ((E > N ? E : N) + 255) / 256;

  hipLaunchKernelGGL(k_setup, dim3(24 + nbN), dim3(256), 0, stream, W1, W2, W3, Wt, cnt, deg, N);
  hipLaunchKernelGGL(k_pos,   dim3(eb),  dim3(256), 0, stream, ei, w, cnt, deg, rc, pos, E, N);
  hipLaunchKernelGGL(k_scan1, dim3(nbN), dim3(256), 0, stream, cnt, offs, bsum, N);
  hipLaunchKernelGGL(k_scan2, dim3(1),   dim3(256), 0, stream, bsum, boff, nbN);
  hipLaunchKernelGGL(k_scan3, dim3(nbN), dim3(256), 0, stream, offs, boff, bsum, deg, dinv, N, nbN);
  hipLaunchKernelGGL(k_fill,  dim3(fb),  dim3(256), 0, stream, rc, pos, w, offs, cnt, dinv, ecf2, E, N);

  const int gb = (N + 63) / 64;
  const int ab = 4 * ((N + 31) / 32);

  hipLaunchKernelGGL((k_gemm<0, float>),  dim3(gb), dim3(256), 0, stream, x, Wt,             Y, N);
  hipLaunchKernelGGL((k_agg<0, __half>),  dim3(ab), dim3(256), 0, stream, Y, offs, ecf2, dinv, b1, pw, h, N);
  hipLaunchKernelGGL((k_gemm<1, __half>), dim3(gb), dim3(256), 0, stream, h, Wt + D * D,     Y, N);
  hipLaunchKernelGGL((k_agg<0, __half>),  dim3(ab), dim3(256), 0, stream, Y, offs, ecf2, dinv, b2, pw, h, N);
  hipLaunchKernelGGL((k_gemm<2, __half>), dim3(gb), dim3(256), 0, stream, h, Wt + 2 * D * D, Y, N);
  hipLaunchKernelGGL((k_agg<1, float>),   dim3(ab), dim3(256), 0, stream, Y, offs, ecf2, dinv, b3, pw, out, N);
}

// Round 2
// 308.985 us; speedup vs baseline: 1.0716x; 1.0716x over previous
//
#include <hip/hip_runtime.h>
#include <hip/hip_fp16.h>
#include <math.h>

constexpr int D = 128;

struct __align__(16) H8 { __half2 h[4]; };

typedef _Float16     half8   __attribute__((ext_vector_type(8)));
typedef float        floatx4 __attribute__((ext_vector_type(4)));
typedef unsigned int uint4v  __attribute__((ext_vector_type(4)));
typedef unsigned int uint2v  __attribute__((ext_vector_type(2)));

// ---------------- preprocessing ----------------

__device__ __forceinline__ int detect64(const int* __restrict__ ei) {
  int z = 0;
#pragma unroll
  for (int i = 0; i < 8; ++i) z |= ei[2 * i + 1];
  return (z == 0) ? 1 : 0;
}

__device__ __forceinline__ void load_edge(const int* __restrict__ ei, int e, int nE,
                                          int m64, int n, int& r, int& c) {
  if (m64) { r = ei[2 * (size_t)e]; c = ei[2 * ((size_t)nE + e)]; }
  else     { r = ei[(size_t)e];     c = ei[(size_t)nE + e]; }
  r = min(max(r, 0), n - 1);
  c = min(max(c, 0), n - 1);
}

// blocks 0..23: transpose W1/W2/W3 (fp32 [k][n]) -> Wt fp16 [n][k], 8 blocks per matrix.
// blocks 24.. : zero packed count|deg accumulator.
__global__ void k_setup(const float* __restrict__ W1, const float* __restrict__ W2,
                        const float* __restrict__ W3, __half* __restrict__ Wt,
                        unsigned long long* __restrict__ cntdeg, int n) {
  int b = blockIdx.x;
  if (b < 24) {
    int m = b >> 3, s = b & 7;
    const float* W = m == 0 ? W1 : (m == 1 ? W2 : W3);
    __half* o = Wt + (size_t)m * D * D;
    int t = threadIdx.x;
    int nn = t & 127;          // output row (input col)
    int kh = t >> 7;           // 0/1: which 8-wide k group
    int k0 = s * 16 + kh * 8;
    H8 hv;
#pragma unroll
    for (int jj = 0; jj < 4; ++jj) {
      float f0 = W[(size_t)(k0 + 2 * jj)     * D + nn];
      float f1 = W[(size_t)(k0 + 2 * jj + 1) * D + nn];
      hv.h[jj] = __floats2half2_rn(f0, f1);
    }
    *(H8*)(o + (size_t)nn * D + k0) = hv;
  } else {
    int i = (b - 24) * 256 + threadIdx.x;
    if (i < n) cntdeg[i] = 0ULL;
  }
}

// ONE u64 atomic per edge: high32 = count (+1), low32 = fixed-point (x65536) weight sum.
// Weight-sum per node << 2^16 so the low word never carries into the count.
// pos = high word of the returned old value.
__global__ void k_pos(const int* __restrict__ ei, const float* __restrict__ w,
                      unsigned long long* __restrict__ cntdeg,
                      int2* __restrict__ rc, int* __restrict__ pos, int nE, int n) {
  int e = blockIdx.x * blockDim.x + threadIdx.x;
  if (e >= nE) return;
  int m64 = detect64(ei);
  int r, c;
  load_edge(ei, e, nE, m64, n, r, c);
  rc[e] = make_int2(r, c);
  float wf = fminf(fmaxf(w[e], 0.0f), 65535.0f);
  unsigned long long pk =
      (1ULL << 32) | (unsigned long long)__float2uint_rn(wf * 65536.0f);
  unsigned long long old = atomicAdd(&cntdeg[c], pk);
  pos[e] = (int)(old >> 32);
}

// exclusive scan of PADDED counts (each node's slot count rounded up to x4
// so every per-node edge range is 16B-aligned for uint4 coef loads)
__global__ void k_scan1(const unsigned long long* __restrict__ cntdeg,
                        int* __restrict__ offs, int* __restrict__ bsum, int n) {
  __shared__ int s[256];
  int t = threadIdx.x;
  int i = blockIdx.x * 256 + t;
  int v = 0;
  if (i < n) {
    int cn = (int)(cntdeg[i] >> 32);
    v = (cn + 3) & ~3;
  }
  s[t] = v;
  __syncthreads();
  for (int off = 1; off < 256; off <<= 1) {
    int x = 0;
    if (t >= off) x = s[t - off];
    __syncthreads();
    if (t >= off) s[t] += x;
    __syncthreads();
  }
  if (i < n) offs[i] = s[t] - v;
  if (t == 255) bsum[blockIdx.x] = s[255];
}

__global__ void k_scan2(const int* __restrict__ bsum, int* __restrict__ boff, int nb) {
  __shared__ int s[256];
  int t = threadIdx.x;
  int v = (t < nb) ? bsum[t] : 0;
  s[t] = v;
  __syncthreads();
  for (int off = 1; off < 256; off <<= 1) {
    int x = 0;
    if (t >= off) x = s[t - off];
    __syncthreads();
    if (t >= off) s[t] += x;
    __syncthreads();
  }
  if (t < nb) boff[t] = s[t] - v;
}

// finish scan + elementwise dinv = rsqrt(1 + weighted_deg)
__global__ void k_scan3(int* __restrict__ offs, const int* __restrict__ boff,
                        const int* __restrict__ bsum,
                        const unsigned long long* __restrict__ cntdeg,
                        float* __restrict__ dinv, int n, int nb) {
  int i = blockIdx.x * 256 + threadIdx.x;
  if (i < n) {
    offs[i] += boff[blockIdx.x];
    float degf = (float)(unsigned int)(cntdeg[i] & 0xffffffffULL) * (1.0f / 65536.0f);
    dinv[i] = rsqrtf(1.0f + degf);
  }
  if (i == 0) offs[n] = boff[nb - 1] + bsum[nb - 1];
}

// scatter packed edges (src<<16 | fp16(dinv[src]*w)) into padded CSR;
// node-parallel part zeroes the pad slots (coef 0 -> no-op in agg).
__global__ void k_fill(const int2* __restrict__ rc, const int* __restrict__ pos,
                       const float* __restrict__ w, const int* __restrict__ offs,
                       const unsigned long long* __restrict__ cntdeg,
                       const float* __restrict__ dinv,
                       unsigned int* __restrict__ ecf2, int nE, int n) {
  int e = blockIdx.x * blockDim.x + threadIdx.x;
  if (e < nE) {
    int2 p = rc[e];
    int idx = offs[p.y] + pos[e];
    float cf = dinv[p.x] * w[e];
    ecf2[idx] = ((unsigned int)p.x << 16) |
                (unsigned int)__half_as_ushort(__float2half_rn(cf));
  }
  if (e < n) {
    int q0 = offs[e] + (int)(cntdeg[e] >> 32), q1 = offs[e + 1];
    for (int q = q0; q < q1; ++q) ecf2[q] = 0;
  }
}

// ---------------- MFMA GEMM: Y(chunk layout) = half( act(A) @ W ) ----------------
template <int ACT>
__device__ __forceinline__ float act_f(float x) {
  if (ACT == 1) return x > 0.f ? x : expm1f(x);
  if (ACT == 2) return 0.5f * x * (1.0f + erff(x * 0.70710678118654752440f));
  return x;
}

template <int ACT, typename AT>
__global__ __launch_bounds__(256) void k_gemm(const AT* __restrict__ A,
                                              const __half* __restrict__ Wt,
                                              __half* __restrict__ Y, int n) {
  const int wave = threadIdx.x >> 6;
  const int lane = threadIdx.x & 63;
  const int np = lane & 15;
  const int quad = lane >> 4;
  const int node = blockIdx.x * 64 + wave * 16 + np;
  const int nc = min(node, n - 1);

  // B-operand frags: b[s] = act(A[node][s*32 + quad*8 .. +7]) as fp16
  half8 b[4];
#pragma unroll
  for (int s = 0; s < 4; ++s) {
    if constexpr (sizeof(AT) == 4) {
      const float* ap = (const float*)A + (size_t)nc * D + s * 32 + quad * 8;
      floatx4 v0 = __builtin_nontemporal_load((const floatx4*)ap);
      floatx4 v1 = __builtin_nontemporal_load((const floatx4*)(ap + 4));
#pragma unroll
      for (int t = 0; t < 4; ++t) {
        b[s][t]     = (_Float16)act_f<ACT>(v0[t]);
        b[s][t + 4] = (_Float16)act_f<ACT>(v1[t]);
      }
    } else {
      // chunk layout: chunk s, node nc, halves quad*8..+7
      half8 raw = __builtin_nontemporal_load(
          (const half8*)((const __half*)A + ((size_t)s * n + nc) * 32 + quad * 8));
#pragma unroll
      for (int t = 0; t < 8; ++t)
        b[s][t] = (_Float16)act_f<ACT>((float)raw[t]);
    }
  }

  floatx4 acc[8];
#pragma unroll
  for (int mt = 0; mt < 8; ++mt) acc[mt] = (floatx4){0.f, 0.f, 0.f, 0.f};

#pragma unroll
  for (int mt = 0; mt < 8; ++mt) {
#pragma unroll
    for (int s = 0; s < 4; ++s) {
      half8 a = *(const half8*)(Wt + (size_t)(mt * 16 + np) * D + s * 32 + quad * 8);
      acc[mt] = __builtin_amdgcn_mfma_f32_16x16x32_f16(a, b[s], acc[mt], 0, 0, 0);
    }
  }

  if (node < n) {
#pragma unroll
    for (int mt = 0; mt < 8; ++mt) {
      __half2 ha = __floats2half2_rn(acc[mt][0], acc[mt][1]);
      __half2 hb = __floats2half2_rn(acc[mt][2], acc[mt][3]);
      uint2v pv;
      pv[0] = *(unsigned int*)&ha;
      pv[1] = *(unsigned int*)&hb;
      int f0 = mt * 16 + quad * 4;
      __builtin_nontemporal_store(
          pv, (uint2v*)(Y + ((size_t)(f0 >> 5) * n + node) * 32 + (f0 & 31)));
    }
  }
}

// -------- aggregation (chunked): per chunk c, OUT[:,c*32..] = dc*(sum coef*Yc[r] + dc*Yc[node]) + b
// node-group = 8 lanes: 2 edge-subs x 4 j-lanes (16B each) => one 64B line per edge gather.
// chunk = blockIdx & 3 -> round-robin block->XCD pins one chunk class per XCD
// (per-XCD gather working set = N*64B = 3.2MB < 4MB L2).
// Inner loop: issue order == consume order (coefs for the whole chunk first, then all
// gathers, then fmas) so in-order vmcnt retire keeps ~10 loads/lane in flight.
__device__ __forceinline__ void fmacc8(float* acc, float c, const H8& y) {
  const _Float16* hp = (const _Float16*)&y;
#pragma unroll
  for (int i = 0; i < 8; ++i) acc[i] = fmaf(c, (float)hp[i], acc[i]);  // v_fma_mix_f32
}

__device__ __forceinline__ float cdecode(unsigned int u) {
  return __half2float(__ushort_as_half((unsigned short)(u & 0xffffu)));
}

__device__ __forceinline__ void gather4(H8* y, uint4v u, const __half* __restrict__ Yc,
                                        int j) {
#pragma unroll
  for (int i = 0; i < 4; ++i)
    y[i] = *(const H8*)(Yc + (size_t)(u[i] >> 16) * 32 + j * 8);
}

__device__ __forceinline__ void accum4(float* acc, uint4v u, const H8* y) {
#pragma unroll
  for (int i = 0; i < 4; ++i) fmacc8(acc, cdecode(u[i]), y[i]);
}

template <int PRELU, typename OutT>
__global__ __launch_bounds__(256) void k_agg(const __half* __restrict__ Y,
                                             const int* __restrict__ offs,
                                             const unsigned int* __restrict__ ecf2,
                                             const float* __restrict__ dinv,
                                             const float* __restrict__ bias,
                                             const float* __restrict__ pw,
                                             OutT* __restrict__ OUT, int n) {
  const int chunk = blockIdx.x & 3;
  const int t = threadIdx.x;
  const int node = (blockIdx.x >> 2) * 32 + (t >> 3);
  const int sub = (t >> 2) & 1;   // edge half-range
  const int j = t & 3;            // 16B piece of the 64B chunk row
  if (node >= n) return;
  const __half* Yc = Y + (size_t)chunk * n * 32;
  float dc = dinv[node];
  float acc[8] = {0.f, 0.f, 0.f, 0.f, 0.f, 0.f, 0.f, 0.f};

  // self term: issue first so it's in flight through the whole loop
  H8 ys{};
  if (sub == 0) ys = *(const H8*)(Yc + (size_t)node * 32 + j * 8);

  int lo = offs[node], hi = offs[node + 1];       // padded to x4, 16B aligned
  int nb4 = (hi - lo) >> 2;
  int em = lo + (((nb4 + 1) >> 1) << 2);          // sub0: [lo,em)  sub1: [em,hi)
  int b0 = sub ? em : lo;
  int be = sub ? hi : em;

  for (int b = b0; b < be; b += 8) {
    bool has2 = (be - b) > 4;
    uint4v u0 = __builtin_nontemporal_load((const uint4v*)(ecf2 + b));
    uint4v u1{};
    if (has2) u1 = __builtin_nontemporal_load((const uint4v*)(ecf2 + b + 4));
    H8 y0[4], y1[4];
    gather4(y0, u0, Yc, j);
    if (has2) gather4(y1, u1, Yc, j);
    accum4(acc, u0, y0);
    if (has2) accum4(acc, u1, y1);
  }
  if (sub == 0) fmacc8(acc, dc, ys);

  // combine the two subs (lanes differ in bit 2): each lane keeps its own 4
  // features and receives the partner's contribution for those 4 only.
  floatx4 b4 = *(const floatx4*)(bias + chunk * 32 + j * 8 + sub * 4);
  float o[4];
#pragma unroll
  for (int i = 0; i < 4; ++i) {
    float mine  = sub ? acc[4 + i] : acc[i];
    float other = sub ? acc[i]     : acc[4 + i];
    float recv = __shfl_xor(other, 4, 64);
    o[i] = dc * (mine + recv) + b4[i];
  }
  if (PRELU) {
    float wv = *pw;
#pragma unroll
    for (int i = 0; i < 4; ++i) o[i] = o[i] >= 0.f ? o[i] : wv * o[i];
  }
  if constexpr (sizeof(OutT) == 4) {
    floatx4 ov = {o[0], o[1], o[2], o[3]};
    __builtin_nontemporal_store(
        ov, (floatx4*)((float*)OUT + (size_t)node * D + chunk * 32 + j * 8 + sub * 4));
  } else {
    __half2 ha = __floats2half2_rn(o[0], o[1]);
    __half2 hb = __floats2half2_rn(o[2], o[3]);
    uint2v pv;
    pv[0] = *(unsigned int*)&ha;
    pv[1] = *(unsigned int*)&hb;
    __builtin_nontemporal_store(
        pv, (uint2v*)((__half*)OUT + ((size_t)chunk * n + node) * 32 + j * 8 + sub * 4));
  }
}

// ---------------- launch ----------------
extern "C" void kernel_launch(void* const* d_in, const int* in_sizes, int n_in,
                              void* d_out, int out_size, void* d_ws, size_t ws_size,
                              hipStream_t stream) {
  const float* x  = (const float*)d_in[0];
  const int*   ei = (const int*)d_in[1];
  const float* w  = (const float*)d_in[2];
  const float* W1 = (const float*)d_in[3];
  const float* b1 = (const float*)d_in[4];
  const float* W2 = (const float*)d_in[5];
  const float* b2 = (const float*)d_in[6];
  const float* W3 = (const float*)d_in[7];
  const float* b3 = (const float*)d_in[8];
  const float* pw = (const float*)d_in[9];
  const int N = in_sizes[0] / D;
  const int E = in_sizes[2];
  float* out = (float*)d_out;

  char* wsb = (char*)d_ws;
  size_t off = 0;
  auto alloc = [&](size_t bytes) {
    void* p = wsb + off;
    off = (off + bytes + 255) & ~(size_t)255;
    return p;
  };
  float*              dinv   = (float*)alloc((size_t)N * 4);
  unsigned long long* cntdeg = (unsigned long long*)alloc((size_t)N * 8);
  int*                offs   = (int*)alloc((size_t)(N + 1) * 4);
  int*                bsum   = (int*)alloc(256 * 4);
  int*                boff   = (int*)alloc(256 * 4);
  unsigned int*       ecf2   = (unsigned int*)alloc(((size_t)E + 3 * (size_t)N + 64) * 4);
  __half*             Wt     = (__half*)alloc((size_t)3 * D * D * 2);
  __half*             Y      = (__half*)alloc((size_t)N * D * 2);
  __half*             h      = (__half*)alloc((size_t)N * D * 2);
  // transient buffers aliased into Y (dead before first GEMM writes Y): 12B/edge < N*D*2
  int2*               rc     = (int2*)Y;
  int*                pos    = (int*)((char*)Y + (size_t)E * 8);

  const int nbN = (N + 255) / 256;
  const int eb  = (E + 255) / 256;
  const int fb  = ((E > N ? E : N) + 255) / 256;

  hipLaunchKernelGGL(k_setup, dim3(24 + nbN), dim3(256), 0, stream, W1, W2, W3, Wt, cntdeg, N);
  hipLaunchKernelGGL(k_pos,   dim3(eb),  dim3(256), 0, stream, ei, w, cntdeg, rc, pos, E, N);
  hipLaunchKernelGGL(k_scan1, dim3(nbN), dim3(256), 0, stream, cntdeg, offs, bsum, N);
  hipLaunchKernelGGL(k_scan2, dim3(1),   dim3(256), 0, stream, bsum, boff, nbN);
  hipLaunchKernelGGL(k_scan3, dim3(nbN), dim3(256), 0, stream, offs, boff, bsum, cntdeg, dinv, N, nbN);
  hipLaunchKernelGGL(k_fill,  dim3(fb),  dim3(256), 0, stream, rc, pos, w, offs, cntdeg, dinv, ecf2, E, N);

  const int gb = (N + 63) / 64;
  const int ab = 4 * ((N + 31) / 32);

  hipLaunchKernelGGL((k_gemm<0, float>),  dim3(gb), dim3(256), 0, stream, x, Wt,             Y, N);
  hipLaunchKernelGGL((k_agg<0, __half>),  dim3(ab), dim3(256), 0, stream, Y, offs, ecf2, dinv, b1, pw, h, N);
  hipLaunchKernelGGL((k_gemm<1, __half>), dim3(gb), dim3(256), 0, stream, h, Wt + D * D,     Y, N);
  hipLaunchKernelGGL((k_agg<0, __half>),  dim3(ab), dim3(256), 0, stream, Y, offs, ecf2, dinv, b2, pw, h, N);
  hipLaunchKernelGGL((k_gemm<2, __half>), dim3(gb), dim3(256), 0, stream, h, Wt + 2 * D * D, Y, N);
  hipLaunchKernelGGL((k_agg<1, float>),   dim3(ab), dim3(256), 0, stream, Y, offs, ecf2, dinv, b3, pw, out, N);
}

// Round 3
// 289.302 us; speedup vs baseline: 1.1445x; 1.0680x over previous
//
#include <hip/hip_runtime.h>
#include <hip/hip_fp16.h>
#include <math.h>

constexpr int D = 128;
constexpr int CAP = 2048;   // LDS coef slots per agg block (8KB)

struct __align__(16) H8 { __half2 h[4]; };

typedef _Float16     half8   __attribute__((ext_vector_type(8)));
typedef float        floatx4 __attribute__((ext_vector_type(4)));
typedef unsigned int uint4v  __attribute__((ext_vector_type(4)));
typedef unsigned int uint2v  __attribute__((ext_vector_type(2)));

// ---------------- preprocessing ----------------

__device__ __forceinline__ int detect64(const int* __restrict__ ei) {
  int z = 0;
#pragma unroll
  for (int i = 0; i < 8; ++i) z |= ei[2 * i + 1];
  return (z == 0) ? 1 : 0;
}

__device__ __forceinline__ void load_edge(const int* __restrict__ ei, int e, int nE,
                                          int m64, int n, int& r, int& c) {
  if (m64) { r = ei[2 * (size_t)e]; c = ei[2 * ((size_t)nE + e)]; }
  else     { r = ei[(size_t)e];     c = ei[(size_t)nE + e]; }
  r = min(max(r, 0), n - 1);
  c = min(max(c, 0), n - 1);
}

// cntdeg is SPREAD: node i lives at cntdeg[i<<3] (one 64B line per node) to kill
// same-line atomic serialization at the shared coherence point.
// blocks 0..23: transpose W1/W2/W3 (fp32 [k][n]) -> Wt fp16 [n][k], 8 blocks per matrix.
// blocks 24.. : zero the spread count|deg accumulator (zero whole 3.2MB, coalesced).
__global__ void k_setup(const float* __restrict__ W1, const float* __restrict__ W2,
                        const float* __restrict__ W3, __half* __restrict__ Wt,
                        unsigned long long* __restrict__ cntdeg, int n8) {
  int b = blockIdx.x;
  if (b < 24) {
    int m = b >> 3, s = b & 7;
    const float* W = m == 0 ? W1 : (m == 1 ? W2 : W3);
    __half* o = Wt + (size_t)m * D * D;
    int t = threadIdx.x;
    int nn = t & 127;          // output row (input col)
    int kh = t >> 7;           // 0/1: which 8-wide k group
    int k0 = s * 16 + kh * 8;
    H8 hv;
#pragma unroll
    for (int jj = 0; jj < 4; ++jj) {
      float f0 = W[(size_t)(k0 + 2 * jj)     * D + nn];
      float f1 = W[(size_t)(k0 + 2 * jj + 1) * D + nn];
      hv.h[jj] = __floats2half2_rn(f0, f1);
    }
    *(H8*)(o + (size_t)nn * D + k0) = hv;
  } else {
    int i = (b - 24) * 256 + threadIdx.x;
    if (i < n8) cntdeg[i] = 0ULL;
  }
}

// ---------------- MFMA GEMM body: Y(chunk layout) = half( act(A) @ W ) -------
template <int ACT>
__device__ __forceinline__ float act_f(float x) {
  if (ACT == 1) return x > 0.f ? x : expm1f(x);
  if (ACT == 2) return 0.5f * x * (1.0f + erff(x * 0.70710678118654752440f));
  return x;
}

template <int ACT, typename AT>
__device__ __forceinline__ void gemm_body(int bid, const AT* __restrict__ A,
                                          const __half* __restrict__ Wt,
                                          __half* __restrict__ Y, int n) {
  const int wave = threadIdx.x >> 6;
  const int lane = threadIdx.x & 63;
  const int np = lane & 15;
  const int quad = lane >> 4;
  const int node = bid * 64 + wave * 16 + np;
  const int nc = min(node, n - 1);

  half8 b[4];
#pragma unroll
  for (int s = 0; s < 4; ++s) {
    if constexpr (sizeof(AT) == 4) {
      const float* ap = (const float*)A + (size_t)nc * D + s * 32 + quad * 8;
      floatx4 v0 = __builtin_nontemporal_load((const floatx4*)ap);
      floatx4 v1 = __builtin_nontemporal_load((const floatx4*)(ap + 4));
#pragma unroll
      for (int t = 0; t < 4; ++t) {
        b[s][t]     = (_Float16)act_f<ACT>(v0[t]);
        b[s][t + 4] = (_Float16)act_f<ACT>(v1[t]);
      }
    } else {
      half8 raw = __builtin_nontemporal_load(
          (const half8*)((const __half*)A + ((size_t)s * n + nc) * 32 + quad * 8));
#pragma unroll
      for (int t = 0; t < 8; ++t)
        b[s][t] = (_Float16)act_f<ACT>((float)raw[t]);
    }
  }

  floatx4 acc[8];
#pragma unroll
  for (int mt = 0; mt < 8; ++mt) acc[mt] = (floatx4){0.f, 0.f, 0.f, 0.f};

#pragma unroll
  for (int mt = 0; mt < 8; ++mt) {
#pragma unroll
    for (int s = 0; s < 4; ++s) {
      half8 a = *(const half8*)(Wt + (size_t)(mt * 16 + np) * D + s * 32 + quad * 8);
      acc[mt] = __builtin_amdgcn_mfma_f32_16x16x32_f16(a, b[s], acc[mt], 0, 0, 0);
    }
  }

  if (node < n) {
#pragma unroll
    for (int mt = 0; mt < 8; ++mt) {
      __half2 ha = __floats2half2_rn(acc[mt][0], acc[mt][1]);
      __half2 hb = __floats2half2_rn(acc[mt][2], acc[mt][3]);
      uint2v pv;
      pv[0] = *(unsigned int*)&ha;
      pv[1] = *(unsigned int*)&hb;
      int f0 = mt * 16 + quad * 4;
      __builtin_nontemporal_store(
          pv, (uint2v*)(Y + ((size_t)(f0 >> 5) * n + node) * 32 + (f0 & 31)));
    }
  }
}

template <int ACT, typename AT>
__global__ __launch_bounds__(256) void k_gemm(const AT* __restrict__ A,
                                              const __half* __restrict__ Wt,
                                              __half* __restrict__ Y, int n) {
  gemm_body<ACT, AT>(blockIdx.x, A, Wt, Y, n);
}

// Fused: blocks [0,gb) run GEMM1 (x @ W1 -> Y); blocks [gb,..) run edge counting.
// GEMM1 is independent of edges and hides under the atomic-bound counting phase.
// ONE u64 atomic per edge: high32 = count (+1), low32 = fixed-point (x65536) weight sum.
__global__ __launch_bounds__(256) void k_posgemm(const float* __restrict__ x,
                                                 const __half* __restrict__ Wt,
                                                 __half* __restrict__ Y,
                                                 const int* __restrict__ ei,
                                                 const float* __restrict__ w,
                                                 unsigned long long* __restrict__ cntdeg,
                                                 int2* __restrict__ rc,
                                                 int* __restrict__ pos,
                                                 int nE, int n, int gb) {
  int b = blockIdx.x;
  if (b < gb) {
    gemm_body<0, float>(b, x, Wt, Y, n);
    return;
  }
  int e = (b - gb) * blockDim.x + threadIdx.x;
  if (e >= nE) return;
  int m64 = detect64(ei);
  int r, c;
  load_edge(ei, e, nE, m64, n, r, c);
  rc[e] = make_int2(r, c);
  float wf = fminf(fmaxf(w[e], 0.0f), 65535.0f);
  unsigned long long pk =
      (1ULL << 32) | (unsigned long long)__float2uint_rn(wf * 65536.0f);
  unsigned long long old = atomicAdd(&cntdeg[(size_t)c << 3], pk);
  pos[e] = (int)(old >> 32);
}

// exclusive scan of PADDED counts (x4 rounding keeps every per-node edge range
// 16B-aligned for uint4 coef loads)
__global__ void k_scan1(const unsigned long long* __restrict__ cntdeg,
                        int* __restrict__ offs, int* __restrict__ bsum, int n) {
  __shared__ int s[256];
  int t = threadIdx.x;
  int i = blockIdx.x * 256 + t;
  int v = 0;
  if (i < n) {
    int cn = (int)(cntdeg[(size_t)i << 3] >> 32);
    v = (cn + 3) & ~3;
  }
  s[t] = v;
  __syncthreads();
  for (int off = 1; off < 256; off <<= 1) {
    int x = 0;
    if (t >= off) x = s[t - off];
    __syncthreads();
    if (t >= off) s[t] += x;
    __syncthreads();
  }
  if (i < n) offs[i] = s[t] - v;
  if (t == 255) bsum[blockIdx.x] = s[255];
}

__global__ void k_scan2(const int* __restrict__ bsum, int* __restrict__ boff, int nb) {
  __shared__ int s[256];
  int t = threadIdx.x;
  int v = (t < nb) ? bsum[t] : 0;
  s[t] = v;
  __syncthreads();
  for (int off = 1; off < 256; off <<= 1) {
    int x = 0;
    if (t >= off) x = s[t - off];
    __syncthreads();
    if (t >= off) s[t] += x;
    __syncthreads();
  }
  if (t < nb) boff[t] = s[t] - v;
}

// finish scan + elementwise dinv = rsqrt(1 + weighted_deg)
__global__ void k_scan3(int* __restrict__ offs, const int* __restrict__ boff,
                        const int* __restrict__ bsum,
                        const unsigned long long* __restrict__ cntdeg,
                        float* __restrict__ dinv, int n, int nb) {
  int i = blockIdx.x * 256 + threadIdx.x;
  if (i < n) {
    offs[i] += boff[blockIdx.x];
    float degf =
        (float)(unsigned int)(cntdeg[(size_t)i << 3] & 0xffffffffULL) * (1.0f / 65536.0f);
    dinv[i] = rsqrtf(1.0f + degf);
  }
  if (i == 0) offs[n] = boff[nb - 1] + bsum[nb - 1];
}

// scatter packed edges (src<<16 | fp16(dinv[src]*w)) into padded CSR;
// node-parallel part zeroes the pad slots (coef 0 -> no-op in agg).
__global__ void k_fill(const int2* __restrict__ rc, const int* __restrict__ pos,
                       const float* __restrict__ w, const int* __restrict__ offs,
                       const unsigned long long* __restrict__ cntdeg,
                       const float* __restrict__ dinv,
                       unsigned int* __restrict__ ecf2, int nE, int n) {
  int e = blockIdx.x * blockDim.x + threadIdx.x;
  if (e < nE) {
    int2 p = rc[e];
    int idx = offs[p.y] + pos[e];
    float cf = dinv[p.x] * w[e];
    ecf2[idx] = ((unsigned int)p.x << 16) |
                (unsigned int)__half_as_ushort(__float2half_rn(cf));
  }
  if (e < n) {
    int q0 = offs[e] + (int)(cntdeg[(size_t)e << 3] >> 32), q1 = offs[e + 1];
    for (int q = q0; q < q1; ++q) ecf2[q] = 0;
  }
}

// -------- aggregation (chunked): per chunk c, OUT[:,c*32..] = dc*(sum coef*Yc[r] + dc*Yc[node]) + b
// node-group = 8 lanes: 2 edge-subs x 4 j-lanes (16B each) => one 64B line per edge gather.
// chunk = blockIdx & 3 -> round-robin block->XCD pins one chunk class per XCD
// (per-XCD gather working set = N*64B = 3.2MB < 4MB L2).
// Coefs for the block's 32 nodes are ONE contiguous padded-CSR segment -> staged
// coalesced into LDS with nt loads (no L2 pollution, off the dependent chain).
// Per-edge chain is then LDS-read -> gather(L2) -> fma only.
__device__ __forceinline__ void fmacc8(float* acc, float c, const H8& y) {
  const _Float16* hp = (const _Float16*)&y;
#pragma unroll
  for (int i = 0; i < 8; ++i) acc[i] = fmaf(c, (float)hp[i], acc[i]);  // v_fma_mix_f32
}

__device__ __forceinline__ float cdecode(unsigned int u) {
  return __half2float(__ushort_as_half((unsigned short)(u & 0xffffu)));
}

__device__ __forceinline__ void gather4(H8* y, uint4v u, const __half* __restrict__ Yc,
                                        int j) {
#pragma unroll
  for (int i = 0; i < 4; ++i)
    y[i] = *(const H8*)(Yc + (size_t)(u[i] >> 16) * 32 + j * 8);
}

__device__ __forceinline__ void accum4(float* acc, uint4v u, const H8* y) {
#pragma unroll
  for (int i = 0; i < 4; ++i) fmacc8(acc, cdecode(u[i]), y[i]);
}

template <int PRELU, typename OutT>
__global__ __launch_bounds__(256) void k_agg(const __half* __restrict__ Y,
                                             const int* __restrict__ offs,
                                             const unsigned int* __restrict__ ecf2,
                                             const float* __restrict__ dinv,
                                             const float* __restrict__ bias,
                                             const float* __restrict__ pw,
                                             OutT* __restrict__ OUT, int n) {
  __shared__ unsigned int sc[CAP];
  const int chunk = blockIdx.x & 3;
  const int t = threadIdx.x;
  const int node0 = (blockIdx.x >> 2) * 32;
  const int node = node0 + (t >> 3);
  const int sub = (t >> 2) & 1;   // edge half-range
  const int j = t & 3;            // 16B piece of the 64B chunk row

  // ---- stage this block's coef segment into LDS (coalesced, nt) ----
  const int seg_lo = offs[node0];
  const int seg_hi = offs[min(node0 + 32, n)];
  const int segN = min(seg_hi - seg_lo, CAP);
  for (int i = t * 4; i < segN; i += 1024) {
    uint4v v = __builtin_nontemporal_load((const uint4v*)(ecf2 + seg_lo + i));
    *(uint4v*)&sc[i] = v;
  }
  __syncthreads();

  if (node >= n) return;
  const __half* Yc = Y + (size_t)chunk * n * 32;
  float dc = dinv[node];
  float acc[8] = {0.f, 0.f, 0.f, 0.f, 0.f, 0.f, 0.f, 0.f};

  // self term: issue early so it's in flight through the loop
  H8 ys{};
  if (sub == 0) ys = *(const H8*)(Yc + (size_t)node * 32 + j * 8);

  int lo = offs[node], hi = offs[node + 1];       // padded to x4, 16B aligned
  int nb4 = (hi - lo) >> 2;
  int em = lo + (((nb4 + 1) >> 1) << 2);          // sub0: [lo,em)  sub1: [em,hi)
  int b0 = sub ? em : lo;
  int be = sub ? hi : em;

  for (int b = b0; b < be; b += 8) {
    bool has2 = (be - b) > 4;
    int k0 = b - seg_lo;
    uint4v u0 = (k0 < CAP) ? *(const uint4v*)&sc[k0]
                           : *(const uint4v*)(ecf2 + b);
    uint4v u1{};
    if (has2) {
      int k1 = k0 + 4;
      u1 = (k1 < CAP) ? *(const uint4v*)&sc[k1]
                      : *(const uint4v*)(ecf2 + b + 4);
    }
    H8 y0[4], y1[4];
    gather4(y0, u0, Yc, j);
    if (has2) gather4(y1, u1, Yc, j);
    accum4(acc, u0, y0);
    if (has2) accum4(acc, u1, y1);
  }
  if (sub == 0) fmacc8(acc, dc, ys);

  // combine the two subs (lanes differ in bit 2): each lane keeps its own 4
  // features and receives the partner's contribution for those 4 only.
  floatx4 b4 = *(const floatx4*)(bias + chunk * 32 + j * 8 + sub * 4);
  float o[4];
#pragma unroll
  for (int i = 0; i < 4; ++i) {
    float mine  = sub ? acc[4 + i] : acc[i];
    float other = sub ? acc[i]     : acc[4 + i];
    float recv = __shfl_xor(other, 4, 64);
    o[i] = dc * (mine + recv) + b4[i];
  }
  if (PRELU) {
    float wv = *pw;
#pragma unroll
    for (int i = 0; i < 4; ++i) o[i] = o[i] >= 0.f ? o[i] : wv * o[i];
  }
  if constexpr (sizeof(OutT) == 4) {
    floatx4 ov = {o[0], o[1], o[2], o[3]};
    __builtin_nontemporal_store(
        ov, (floatx4*)((float*)OUT + (size_t)node * D + chunk * 32 + j * 8 + sub * 4));
  } else {
    __half2 ha = __floats2half2_rn(o[0], o[1]);
    __half2 hb = __floats2half2_rn(o[2], o[3]);
    uint2v pv;
    pv[0] = *(unsigned int*)&ha;
    pv[1] = *(unsigned int*)&hb;
    __builtin_nontemporal_store(
        pv, (uint2v*)((__half*)OUT + ((size_t)chunk * n + node) * 32 + j * 8 + sub * 4));
  }
}

// ---------------- launch ----------------
extern "C" void kernel_launch(void* const* d_in, const int* in_sizes, int n_in,
                              void* d_out, int out_size, void* d_ws, size_t ws_size,
                              hipStream_t stream) {
  const float* x  = (const float*)d_in[0];
  const int*   ei = (const int*)d_in[1];
  const float* w  = (const float*)d_in[2];
  const float* W1 = (const float*)d_in[3];
  const float* b1 = (const float*)d_in[4];
  const float* W2 = (const float*)d_in[5];
  const float* b2 = (const float*)d_in[6];
  const float* W3 = (const float*)d_in[7];
  const float* b3 = (const float*)d_in[8];
  const float* pw = (const float*)d_in[9];
  const int N = in_sizes[0] / D;
  const int E = in_sizes[2];
  float* out = (float*)d_out;

  char* wsb = (char*)d_ws;
  size_t off = 0;
  auto alloc = [&](size_t bytes) {
    void* p = wsb + off;
    off = (off + bytes + 255) & ~(size_t)255;
    return p;
  };
  float*              dinv   = (float*)alloc((size_t)N * 4);
  unsigned long long* cntdeg = (unsigned long long*)alloc((size_t)N * 64);  // spread, 1 node/64B line
  int*                offs   = (int*)alloc((size_t)(N + 1) * 4);
  int*                bsum   = (int*)alloc(256 * 4);
  int*                boff   = (int*)alloc(256 * 4);
  unsigned int*       ecf2   = (unsigned int*)alloc(((size_t)E + 3 * (size_t)N + 64) * 4);
  __half*             Wt     = (__half*)alloc((size_t)3 * D * D * 2);
  __half*             Y      = (__half*)alloc((size_t)N * D * 2);
  __half*             h      = (__half*)alloc((size_t)N * D * 2);
  int2*               rc     = (int2*)alloc((size_t)E * 8);
  int*                pos    = (int*)alloc((size_t)E * 4);

  const int nbN = (N + 255) / 256;
  const int eb  = (E + 255) / 256;
  const int fb  = ((E > N ? E : N) + 255) / 256;
  const int n8  = N * 8;
  const int zb  = (n8 + 255) / 256;
  const int gb  = (N + 63) / 64;
  const int ab  = 4 * ((N + 31) / 32);

  hipLaunchKernelGGL(k_setup,   dim3(24 + zb), dim3(256), 0, stream, W1, W2, W3, Wt, cntdeg, n8);
  hipLaunchKernelGGL(k_posgemm, dim3(gb + eb), dim3(256), 0, stream, x, Wt, Y, ei, w, cntdeg,
                     rc, pos, E, N, gb);
  hipLaunchKernelGGL(k_scan1,   dim3(nbN), dim3(256), 0, stream, cntdeg, offs, bsum, N);
  hipLaunchKernelGGL(k_scan2,   dim3(1),   dim3(256), 0, stream, bsum, boff, nbN);
  hipLaunchKernelGGL(k_scan3,   dim3(nbN), dim3(256), 0, stream, offs, boff, bsum, cntdeg, dinv, N, nbN);
  hipLaunchKernelGGL(k_fill,    dim3(fb),  dim3(256), 0, stream, rc, pos, w, offs, cntdeg, dinv, ecf2, E, N);

  hipLaunchKernelGGL((k_agg<0, __half>),  dim3(ab), dim3(256), 0, stream, Y, offs, ecf2, dinv, b1, pw, h, N);
  hipLaunchKernelGGL((k_gemm<1, __half>), dim3(gb), dim3(256), 0, stream, h, Wt + D * D,     Y, N);
  hipLaunchKernelGGL((k_agg<0, __half>),  dim3(ab), dim3(256), 0, stream, Y, offs, ecf2, dinv, b2, pw, h, N);
  hipLaunchKernelGGL((k_gemm<2, __half>), dim3(gb), dim3(256), 0, stream, h, Wt + 2 * D * D, Y, N);
  hipLaunchKernelGGL((k_agg<1, float>),   dim3(ab), dim3(256), 0, stream, Y, offs, ecf2, dinv, b3, pw, out, N);
}